// Round 2
// baseline (2741.082 us; speedup 1.0000x reference)
//
#include <hip/hip_runtime.h>
#include <hip/hip_bf16.h>

// Problem: B=256, L=2048, H=128, V=32000, THR=0.4, LN_EPS=1e-5
// All inputs are float32 (per reference); output float32.
// Key insight: h_all[b,t] depends only on token id seq[b,t] -> precompute
// H_table[32000,128] once, scan gathers rows. All gate-feeding math in fp32.

#define BB 256
#define LL 2048
#define HH 128
#define VV 32000

// ---------------------------------------------------------------------------
// Kernel A: H_table[v,:] = LN(e + relu(e@W1+b1)@W2 + b2), e = embed[v]
// also kkinv[v] = ( ||h||^2 , 1/(||h||^2 + 1e-6) )
// 256 blocks x 256 threads, grid-stride over 32000 rows (125 rows/block).
// W1 column per thread in regs (128), W2 half-column per thread in regs (128).
// ---------------------------------------------------------------------------
__global__ __launch_bounds__(256, 1) void build_htab_kernel(
    const float* __restrict__ embed,
    const float* __restrict__ W1,
    const float* __restrict__ b1,
    const float* __restrict__ W2,
    const float* __restrict__ b2,
    const float* __restrict__ gamma,
    const float* __restrict__ beta,
    float* __restrict__ Htab,
    float2* __restrict__ kkinv)
{
  const int tid = threadIdx.x;
  const int j   = tid & 127;
  const int h2  = tid >> 7;

  float w1r[128];
#pragma unroll
  for (int m = 0; m < 128; ++m) w1r[m] = W1[m * 256 + tid];
  float w2r[128];
#pragma unroll
  for (int n = 0; n < 128; ++n) w2r[n] = W2[(h2 * 128 + n) * 128 + j];

  const float b1n = b1[tid];
  const float b2j = b2[j];
  const float gj  = gamma[j];
  const float bj  = beta[j];

  __shared__ __align__(16) float e_s[128];
  __shared__ __align__(16) float a_s[256];
  __shared__ float p_s[2][128];
  __shared__ float red[8];

  for (int v = blockIdx.x; v < VV; v += gridDim.x) {
    if (tid < 128) e_s[tid] = embed[(size_t)v * 128 + tid];
    __syncthreads();

    // phase 1: t1_n = b1_n + sum_m e[m]*W1[m,n], relu
    float acc[4] = {b1n, 0.f, 0.f, 0.f};
#pragma unroll
    for (int q = 0; q < 32; ++q) {
      float4 ev = *(const float4*)&e_s[4 * q];
      float t = ev.x * w1r[4 * q + 0];
      t = fmaf(ev.y, w1r[4 * q + 1], t);
      t = fmaf(ev.z, w1r[4 * q + 2], t);
      t = fmaf(ev.w, w1r[4 * q + 3], t);
      acc[q & 3] += t;
    }
    float a = fmaxf((acc[0] + acc[1]) + (acc[2] + acc[3]), 0.0f);
    a_s[tid] = a;
    __syncthreads();

    // phase 2: ff_j = b2_j + sum_n relu(t1)_n * W2[n,j]  (split over halves)
    float pacc[4] = {0.f, 0.f, 0.f, 0.f};
#pragma unroll
    for (int q = 0; q < 32; ++q) {
      float4 av = *(const float4*)&a_s[h2 * 128 + 4 * q];
      float t = av.x * w2r[4 * q + 0];
      t = fmaf(av.y, w2r[4 * q + 1], t);
      t = fmaf(av.z, w2r[4 * q + 2], t);
      t = fmaf(av.w, w2r[4 * q + 3], t);
      pacc[q & 3] += t;
    }
    p_s[h2][j] = (pacc[0] + pacc[1]) + (pacc[2] + pacc[3]);
    __syncthreads();

    float y = 0.0f;
    if (tid < 128) {
      float ff = p_s[0][tid] + p_s[1][tid] + b2j;
      y = e_s[tid] + ff;
    }
    // LayerNorm, two-pass (matches reference mean((y-mu)^2))
    float s1 = y;
#pragma unroll
    for (int d = 1; d < 64; d <<= 1) s1 += __shfl_xor(s1, d);
    if (tid < 128 && (tid & 63) == 0) red[tid >> 6] = s1;
    __syncthreads();
    float mu = (red[0] + red[1]) * (1.0f / 128.0f);
    float dy = (tid < 128) ? (y - mu) : 0.0f;
    float s2 = dy * dy;
#pragma unroll
    for (int d = 1; d < 64; d <<= 1) s2 += __shfl_xor(s2, d);
    if (tid < 128 && (tid & 63) == 0) red[2 + (tid >> 6)] = s2;
    __syncthreads();
    float hv = 0.0f;
    if (tid < 128) {
      float var = (red[2] + red[3]) * (1.0f / 128.0f);
      hv = dy * (1.0f / sqrtf(var + 1e-5f)) * gj + bj;
      Htab[(size_t)v * 128 + tid] = hv;
    }
    float q2 = hv * hv;
#pragma unroll
    for (int d = 1; d < 64; d <<= 1) q2 += __shfl_xor(q2, d);
    if (tid < 128 && (tid & 63) == 0) red[4 + (tid >> 6)] = q2;
    __syncthreads();
    if (tid == 0) {
      float kk = red[4] + red[5];
      kkinv[v] = make_float2(kk, 1.0f / (kk + 1e-6f));
    }
    __syncthreads();  // protect e_s/a_s/red for next row
  }
}

// ---------------------------------------------------------------------------
// Kernel B: per-batch sequential scan. 256 blocks (1/CU) x 256 threads.
// Thread (i = tid>>1, half = tid&1) owns M[i][64*half .. +64] in 64 VGPRs.
// Double-buffered k prefetch (registers), one barrier per step.
// Epilogue: r = M_fin @ h(seq[b,L-1]);  rr = r @ Wrp + brp  (fp32 to ws).
// ---------------------------------------------------------------------------
__device__ __forceinline__ void scan_step(
    float4 (&kc)[16], float ki_c, float kk_c, float inv_c,
    float4 (&kn)[16], float& ki_n, float& kk_n, float& inv_n,
    int t_next, int parity,
    const int* seq_s, const float* __restrict__ Htab,
    const float2* __restrict__ kkinv,
    float (&M)[64], float (*red)[4],
    int i, int halfBase, int wv, int lane)
{
  // prefetch k for t_next
  int tokn = seq_s[t_next];
  const float4* hp = (const float4*)(Htab + (size_t)tokn * 128) + halfBase;
#pragma unroll
  for (int m = 0; m < 16; ++m) kn[m] = hp[m];
  ki_n = Htab[(size_t)tokn * 128 + i];
  float2 kv = kkinv[tokn];
  kk_n = kv.x; inv_n = kv.y;

  // vp_i partial over own 64 columns
  float acc[4] = {0.f, 0.f, 0.f, 0.f};
#pragma unroll
  for (int m = 0; m < 16; ++m) {
    float t = kc[m].x * M[4 * m + 0];
    t = fmaf(kc[m].y, M[4 * m + 1], t);
    t = fmaf(kc[m].z, M[4 * m + 2], t);
    t = fmaf(kc[m].w, M[4 * m + 3], t);
    acc[m & 3] += t;
  }
  float vp = (acc[0] + acc[1]) + (acc[2] + acc[3]);
  vp += __shfl_xor(vp, 1);           // pair (same row, other half)

  float e = fmaf(-vp, inv_c, ki_c);  // e_i = k_i - vp_i/(kk+1e-6)

  float se = e * e;                  // wave butterfly: 2 * sum_{rows in wave}
#pragma unroll
  for (int d = 1; d < 64; d <<= 1) se += __shfl_xor(se, d);
  if (lane == 0) red[parity][wv] = se;
  __syncthreads();
  float ne2 = (red[parity][0] + red[parity][1]) + (red[parity][2] + red[parity][3]);

  // gate: ||e|| > 0.4*||v||  (sqrt form = closest to reference semantics)
  if (sqrtf(ne2 * 0.5f) > 0.4f * sqrtf(kk_c)) {
#pragma unroll
    for (int m = 0; m < 16; ++m) {
      M[4 * m + 0] = fmaf(e, kc[m].x, M[4 * m + 0]);
      M[4 * m + 1] = fmaf(e, kc[m].y, M[4 * m + 1]);
      M[4 * m + 2] = fmaf(e, kc[m].z, M[4 * m + 2]);
      M[4 * m + 3] = fmaf(e, kc[m].w, M[4 * m + 3]);
    }
  }
}

__global__ __launch_bounds__(256, 1) void scan_kernel(
    const int* __restrict__ seq,
    const float* __restrict__ Htab,
    const float2* __restrict__ kkinv,
    const float* __restrict__ Wrp,
    const float* __restrict__ brp,
    float* __restrict__ rr)
{
  const int b = blockIdx.x;
  const int tid = threadIdx.x;
  const int i = tid >> 1;
  const int halfBase = (tid & 1) * 16;
  const int wv = tid >> 6;
  const int lane = tid & 63;

  __shared__ int seq_s[LL];
  __shared__ float red[2][4];
  __shared__ __align__(16) float r_s[128];
  __shared__ float p2_s[2][128];

  for (int t = tid; t < LL; t += 256) seq_s[t] = seq[(size_t)b * LL + t];
  __syncthreads();

  float M[64];
#pragma unroll
  for (int m = 0; m < 64; ++m) M[m] = 0.0f;

  float4 kA[16], kB[16];
  float kiA, kkA, invA, kiB, kkB, invB;

  {  // prefetch t = 0
    int tok = seq_s[0];
    const float4* hp = (const float4*)(Htab + (size_t)tok * 128) + halfBase;
#pragma unroll
    for (int m = 0; m < 16; ++m) kA[m] = hp[m];
    kiA = Htab[(size_t)tok * 128 + i];
    float2 kv = kkinv[tok];
    kkA = kv.x; invA = kv.y;
  }

  // steps t = 0 .. 2045 in pairs
  for (int t = 0; t < LL - 2; t += 2) {
    scan_step(kA, kiA, kkA, invA, kB, kiB, kkB, invB, t + 1, 0,
              seq_s, Htab, kkinv, M, red, i, halfBase, wv, lane);
    scan_step(kB, kiB, kkB, invB, kA, kiA, kkA, invA, t + 2, 1,
              seq_s, Htab, kkinv, M, red, i, halfBase, wv, lane);
  }
  // step t = 2046, prefetch t = 2047 (used only for final matvec)
  scan_step(kA, kiA, kkA, invA, kB, kiB, kkB, invB, LL - 1, 0,
            seq_s, Htab, kkinv, M, red, i, halfBase, wv, lane);

  // r = M_fin @ h(seq[b, L-1])
  {
    float acc[4] = {0.f, 0.f, 0.f, 0.f};
#pragma unroll
    for (int m = 0; m < 16; ++m) {
      float t = kB[m].x * M[4 * m + 0];
      t = fmaf(kB[m].y, M[4 * m + 1], t);
      t = fmaf(kB[m].z, M[4 * m + 2], t);
      t = fmaf(kB[m].w, M[4 * m + 3], t);
      acc[m & 3] += t;
    }
    float vp = (acc[0] + acc[1]) + (acc[2] + acc[3]);
    vp += __shfl_xor(vp, 1);
    if ((tid & 1) == 0) r_s[i] = vp;
  }
  __syncthreads();

  // rr[b,:] = r @ Wrp + brp   (fp32)
  const int j = tid & 127;
  const int h2 = tid >> 7;
  float pac[2] = {0.f, 0.f};
#pragma unroll
  for (int m = 0; m < 64; ++m) {
    pac[m & 1] = fmaf(r_s[h2 * 64 + m],
                      Wrp[(size_t)(h2 * 64 + m) * 128 + j], pac[m & 1]);
  }
  p2_s[h2][j] = pac[0] + pac[1];
  __syncthreads();
  if (tid < 128) {
    rr[(size_t)b * 128 + tid] = p2_s[0][tid] + p2_s[1][tid] + brp[tid];
  }
}

// ---------------------------------------------------------------------------
// Kernel C: out[b,v] = sum_h rr[b,h]*Wout[h,v] + bout[v]   -> fp32
// grid (500, 4): v-chunk 64, b-tile 64. rr tile staged fp32 in LDS (32 KB).
// ---------------------------------------------------------------------------
__global__ __launch_bounds__(256, 1) void out_kernel(
    const float* __restrict__ rr,
    const float* __restrict__ Wout,
    const float* __restrict__ bout,
    float* __restrict__ out)
{
  const int tid = threadIdx.x;
  const int v = blockIdx.x * 64 + (tid & 63);
  const int bg = tid >> 6;             // 0..3, wave-uniform
  const int b0 = blockIdx.y * 64;

  __shared__ float4 rs4[64][32];       // [b][h/4], 32 KB
  for (int idx = tid; idx < 2048; idx += 256) {
    int bb = idx >> 5, q = idx & 31;
    rs4[bb][q] = ((const float4*)rr)[(size_t)(b0 + bb) * 32 + q];
  }
  __syncthreads();

  float acc[16];
#pragma unroll
  for (int m = 0; m < 16; ++m) acc[m] = 0.0f;

  for (int h4 = 0; h4 < 32; ++h4) {
    float w0 = Wout[(size_t)(4 * h4 + 0) * VV + v];
    float w1 = Wout[(size_t)(4 * h4 + 1) * VV + v];
    float w2 = Wout[(size_t)(4 * h4 + 2) * VV + v];
    float w3 = Wout[(size_t)(4 * h4 + 3) * VV + v];
#pragma unroll
    for (int m = 0; m < 16; ++m) {
      float4 rv = rs4[bg * 16 + m][h4];   // broadcast (lane-uniform addr)
      float t = rv.x * w0;
      t = fmaf(rv.y, w1, t);
      t = fmaf(rv.z, w2, t);
      t = fmaf(rv.w, w3, t);
      acc[m] += t;
    }
  }
  float bo = bout[v];
#pragma unroll
  for (int m = 0; m < 16; ++m) {
    out[(size_t)(b0 + bg * 16 + m) * VV + v] = acc[m] + bo;
  }
}

// ---------------------------------------------------------------------------
extern "C" void kernel_launch(void* const* d_in, const int* in_sizes, int n_in,
                              void* d_out, int out_size, void* d_ws, size_t ws_size,
                              hipStream_t stream)
{
  const int* seq      = (const int*)d_in[0];
  const float* embed  = (const float*)d_in[1];
  const float* W1     = (const float*)d_in[2];
  const float* b1     = (const float*)d_in[3];
  const float* W2     = (const float*)d_in[4];
  const float* b2     = (const float*)d_in[5];
  const float* gamma  = (const float*)d_in[6];
  const float* beta   = (const float*)d_in[7];
  const float* Wrp    = (const float*)d_in[8];
  const float* brp    = (const float*)d_in[9];
  const float* Wout   = (const float*)d_in[10];
  const float* bout   = (const float*)d_in[11];
  float* out          = (float*)d_out;

  char* ws = (char*)d_ws;
  float*  Htab  = (float*)ws;                               // 16,384,000 B
  float2* kkinv = (float2*)(ws + 16384000);                 //    256,000 B
  float*  rr    = (float*)(ws + 16384000 + 256000);         //    131,072 B

  hipLaunchKernelGGL(build_htab_kernel, dim3(256), dim3(256), 0, stream,
                     embed, W1, b1, W2, b2, gamma, beta, Htab, kkinv);
  hipLaunchKernelGGL(scan_kernel, dim3(BB), dim3(256), 0, stream,
                     seq, Htab, kkinv, Wrp, brp, rr);
  hipLaunchKernelGGL(out_kernel, dim3(VV / 64, 4), dim3(256), 0, stream,
                     rr, Wout, bout, out);
}

// Round 3
// 2091.581 us; speedup vs baseline: 1.3105x; 1.3105x over previous
//
#include <hip/hip_runtime.h>
#include <hip/hip_bf16.h>

// B=256, L=2048, H=128, V=32000, THR=0.4, LN_EPS=1e-5. All fp32.
// Htab2[v] = 136 floats: [0..127]=h(v), [128]=||h||^2, [129]=1/(||h||^2+1e-6).
// Scan: M in VGPRs, k rows DMA'd into a 3-slot LDS ring (global_load_lds),
// one barrier per step, DPP-shortened reduction.

#define BB 256
#define LL 2048
#define HH 128
#define VV 32000
#define RS 136   // Htab2 row stride (floats), 544 B = 34 * 16 B

__device__ __forceinline__ void dma16(const float* g, float* l) {
  __builtin_amdgcn_global_load_lds(
      (const __attribute__((address_space(1))) void*)g,
      (__attribute__((address_space(3))) void*)l,
      16, 0, 0);
}

template <int CTRL>
__device__ __forceinline__ float dppadd(float x) {
  int y = __builtin_amdgcn_update_dpp(0, __float_as_int(x), CTRL, 0xF, 0xF, true);
  return x + __int_as_float(y);
}

// ---------------------------------------------------------------------------
// Kernel A: Htab2 row = LN(e + relu(e@W1+b1)@W2 + b2) (+ kk, inv).
// W1 column per thread in regs (128 VGPR); W2 staged in LDS as float4
// chunks w2q[n4][j] = W2[4n4..4n4+3][j] (conflict-free b128 reads).
// ---------------------------------------------------------------------------
__global__ __launch_bounds__(256, 1) void build_htab_kernel(
    const float* __restrict__ embed,
    const float* __restrict__ W1,
    const float* __restrict__ b1,
    const float* __restrict__ W2,
    const float* __restrict__ b2,
    const float* __restrict__ gamma,
    const float* __restrict__ beta,
    float* __restrict__ Htab2)
{
  const int tid = threadIdx.x;
  const int j   = tid & 127;
  const int h2  = tid >> 7;

  float w1r[128];
#pragma unroll
  for (int m = 0; m < 128; ++m) w1r[m] = W1[m * 256 + tid];

  const float b1n = b1[tid];
  const float b2j = b2[j];
  const float gj  = gamma[j];
  const float bj  = beta[j];

  __shared__ __align__(16) float4 w2q[64][128];   // 128 KiB
  __shared__ __align__(16) float e_s[128];
  __shared__ __align__(16) float a_s[256];
  __shared__ float p_s[2][128];
  __shared__ float red[8];

  for (int idx = tid; idx < 8192; idx += 256) {
    int n4 = idx >> 7, jj = idx & 127;
    float4 w;
    w.x = W2[(size_t)(4 * n4 + 0) * 128 + jj];
    w.y = W2[(size_t)(4 * n4 + 1) * 128 + jj];
    w.z = W2[(size_t)(4 * n4 + 2) * 128 + jj];
    w.w = W2[(size_t)(4 * n4 + 3) * 128 + jj];
    w2q[n4][jj] = w;
  }
  __syncthreads();

  for (int v = blockIdx.x; v < VV; v += gridDim.x) {
    if (tid < 128) e_s[tid] = embed[(size_t)v * 128 + tid];
    __syncthreads();

    // phase 1: a = relu(b1 + e @ W1)   (thread owns column tid)
    float acc[4] = {b1n, 0.f, 0.f, 0.f};
#pragma unroll
    for (int q = 0; q < 32; ++q) {
      float4 ev = *(const float4*)&e_s[4 * q];
      float t = ev.x * w1r[4 * q + 0];
      t = fmaf(ev.y, w1r[4 * q + 1], t);
      t = fmaf(ev.z, w1r[4 * q + 2], t);
      t = fmaf(ev.w, w1r[4 * q + 3], t);
      acc[q & 3] += t;
    }
    float a = fmaxf((acc[0] + acc[1]) + (acc[2] + acc[3]), 0.0f);
    a_s[tid] = a;
    __syncthreads();

    // phase 2: ff_j partial over n = h2*128 .. +127 from LDS W2
    float p0 = 0.f, p1 = 0.f, p2v = 0.f, p3 = 0.f;
#pragma unroll
    for (int q = 0; q < 32; ++q) {
      int n4 = h2 * 32 + q;
      float4 av = *(const float4*)&a_s[4 * n4];
      float4 wq = w2q[n4][j];
      p0 = fmaf(av.x, wq.x, p0);
      p1 = fmaf(av.y, wq.y, p1);
      p2v = fmaf(av.z, wq.z, p2v);
      p3 = fmaf(av.w, wq.w, p3);
    }
    p_s[h2][j] = (p0 + p1) + (p2v + p3);
    __syncthreads();

    float y = 0.0f;
    if (tid < 128) {
      float ff = p_s[0][tid] + p_s[1][tid] + b2j;
      y = e_s[tid] + ff;
    }
    float s1 = y;
#pragma unroll
    for (int d = 1; d < 64; d <<= 1) s1 += __shfl_xor(s1, d);
    if (tid < 128 && (tid & 63) == 0) red[tid >> 6] = s1;
    __syncthreads();
    float mu = (red[0] + red[1]) * (1.0f / 128.0f);
    float dy = (tid < 128) ? (y - mu) : 0.0f;
    float s2 = dy * dy;
#pragma unroll
    for (int d = 1; d < 64; d <<= 1) s2 += __shfl_xor(s2, d);
    if (tid < 128 && (tid & 63) == 0) red[2 + (tid >> 6)] = s2;
    __syncthreads();
    float hv = 0.0f;
    if (tid < 128) {
      float var = (red[2] + red[3]) * (1.0f / 128.0f);
      hv = dy * (1.0f / sqrtf(var + 1e-5f)) * gj + bj;
      Htab2[(size_t)v * RS + tid] = hv;
    }
    float q2 = hv * hv;
#pragma unroll
    for (int d = 1; d < 64; d <<= 1) q2 += __shfl_xor(q2, d);
    if (tid < 128 && (tid & 63) == 0) red[4 + (tid >> 6)] = q2;
    __syncthreads();
    if (tid == 0) {
      float kk = red[4] + red[5];
      Htab2[(size_t)v * RS + 128] = kk;
      Htab2[(size_t)v * RS + 129] = 1.0f / (kk + 1e-6f);
    }
    __syncthreads();
  }
}

// ---------------------------------------------------------------------------
// Kernel B: per-batch scan. 256 blocks x 256 threads, 1 block/CU.
// Thread (i=tid>>1, half=tid&1) owns M[i][64*half..+63] in 64 VGPRs.
// 3-slot LDS k-ring, async DMA per step, single barrier per step.
// ---------------------------------------------------------------------------
__global__ __launch_bounds__(256, 1) void scan_kernel(
    const int* __restrict__ seq,
    const float* __restrict__ Htab2,
    const float* __restrict__ Wrp,
    const float* __restrict__ brp,
    float* __restrict__ rr)
{
  const int b    = blockIdx.x;
  const int tid  = threadIdx.x;
  const int i    = tid >> 1;
  const int half = tid & 1;
  const int lane = tid & 63;
  const int wv   = tid >> 6;

  __shared__ int seq_s[LL];
  __shared__ __align__(16) float slots[3][RS];
  __shared__ __align__(16) float red[2][4];
  __shared__ __align__(16) float r_s[128];
  __shared__ float p2_s[2][128];

  for (int t = tid; t < LL; t += 256) seq_s[t] = seq[(size_t)b * LL + t];
  __syncthreads();

  // prologue: DMA k0 -> slot0, k1 -> slot1 (all waves redundantly; benign)
  if (lane < 34) {
    int t0 = seq_s[0], t1 = seq_s[1];
    dma16(Htab2 + (size_t)t0 * RS + lane * 4, &slots[0][lane * 4]);
    dma16(Htab2 + (size_t)t1 * RS + lane * 4, &slots[1][lane * 4]);
  }
  __syncthreads();  // drains DMA

  float M[64];
#pragma unroll
  for (int m = 0; m < 64; ++m) M[m] = 0.f;

  float4 kreg[16];
  {
    const float4* kp = (const float4*)&slots[0][half * 64];
#pragma unroll
    for (int m = 0; m < 16; ++m) kreg[m] = kp[m];
  }
  float ki  = slots[0][i];
  float kk  = slots[0][128];
  float inv = slots[0][129];

  int sc = 0, sn = 1, sd = 2;   // current / next / dma-target slots

  auto step = [&](int t, int p, bool doDma) {
    // ---- phase A: vp, e, ||e||^2 reduction ----
    float a0 = 0.f, a1 = 0.f, a2 = 0.f, a3 = 0.f;
#pragma unroll
    for (int m = 0; m < 16; ++m) {
      float4 kv = kreg[m];
      a0 = fmaf(kv.x, M[4 * m + 0], a0);
      a1 = fmaf(kv.y, M[4 * m + 1], a1);
      a2 = fmaf(kv.z, M[4 * m + 2], a2);
      a3 = fmaf(kv.w, M[4 * m + 3], a3);
    }
    float vp = (a0 + a1) + (a2 + a3);
    vp = dppadd<0xB1>(vp);                 // pair halves (xor1)
    float e = fmaf(-vp, inv, ki);
    // e duplicated across half-pairs -> skip xor1, sum 32 distinct rows/wave
    float s = e * e;
    s = dppadd<0x4E>(s);                   // quad_perm [2,3,0,1] : ^2
    s = dppadd<0x141>(s);                  // row_half_mirror     : 4-row group
    s = dppadd<0x140>(s);                  // row_mirror          : 8-row group
    s += __shfl_xor(s, 16);
    s += __shfl_xor(s, 32);
    if (lane == 0) red[p][wv] = s;
    __syncthreads();                        // drains DMA(k_{t+1}); red visible

    // ---- phase B ----
    if (doDma) {                            // DMA k_{t+2} -> slot sd
      if (lane < 34) {
        int tk = seq_s[t + 2];
        dma16(Htab2 + (size_t)tk * RS + lane * 4, &slots[sd][lane * 4]);
      }
    }
    float4 rv = *(const float4*)red[p];
    float ne2 = (rv.x + rv.y) + (rv.z + rv.w);
    if (sqrtf(ne2) > 0.4f * sqrtf(kk)) {
#pragma unroll
      for (int m = 0; m < 16; ++m) {
        float4 kv = kreg[m];
        M[4 * m + 0] = fmaf(e, kv.x, M[4 * m + 0]);
        M[4 * m + 1] = fmaf(e, kv.y, M[4 * m + 1]);
        M[4 * m + 2] = fmaf(e, kv.z, M[4 * m + 2]);
        M[4 * m + 3] = fmaf(e, kv.w, M[4 * m + 3]);
      }
    }
    // refill kreg <- k_{t+1} (slot sn); overlaps update FMAs
    {
      const float4* kp = (const float4*)&slots[sn][half * 64];
#pragma unroll
      for (int m = 0; m < 16; ++m) kreg[m] = kp[m];
      ki  = slots[sn][i];
      kk  = slots[sn][128];
      inv = slots[sn][129];
    }
    int t0 = sc; sc = sn; sn = sd; sd = t0;   // rotate ring
  };

  for (int t = 0; t < LL - 2; t += 2) {   // steps 0..2045
    step(t, 0, true);
    step(t + 1, 1, true);
  }
  step(LL - 2, 0, false);                  // step 2046 (no DMA for 2048)

  // r = M_fin @ h(seq[b, L-1])  (kreg = k_2047)
  {
    float a0 = 0.f, a1 = 0.f, a2 = 0.f, a3 = 0.f;
#pragma unroll
    for (int m = 0; m < 16; ++m) {
      float4 kv = kreg[m];
      a0 = fmaf(kv.x, M[4 * m + 0], a0);
      a1 = fmaf(kv.y, M[4 * m + 1], a1);
      a2 = fmaf(kv.z, M[4 * m + 2], a2);
      a3 = fmaf(kv.w, M[4 * m + 3], a3);
    }
    float vp = (a0 + a1) + (a2 + a3);
    vp = dppadd<0xB1>(vp);
    if (half == 0) r_s[i] = vp;
  }
  __syncthreads();

  // rr[b,:] = r @ Wrp + brp
  const int j  = tid & 127;
  const int h2 = tid >> 7;
  float pac[2] = {0.f, 0.f};
#pragma unroll
  for (int m = 0; m < 64; ++m) {
    pac[m & 1] = fmaf(r_s[h2 * 64 + m],
                      Wrp[(size_t)(h2 * 64 + m) * 128 + j], pac[m & 1]);
  }
  p2_s[h2][j] = pac[0] + pac[1];
  __syncthreads();
  if (tid < 128) {
    rr[(size_t)b * 128 + tid] = p2_s[0][tid] + p2_s[1][tid] + brp[tid];
  }
}

// ---------------------------------------------------------------------------
// Kernel C: out[b,v] = rr[b,:] @ Wout[:,v] + bout[v]
// ---------------------------------------------------------------------------
__global__ __launch_bounds__(256, 1) void out_kernel(
    const float* __restrict__ rr,
    const float* __restrict__ Wout,
    const float* __restrict__ bout,
    float* __restrict__ out)
{
  const int tid = threadIdx.x;
  const int v = blockIdx.x * 64 + (tid & 63);
  const int bg = tid >> 6;
  const int b0 = blockIdx.y * 64;

  __shared__ float4 rs4[64][32];
  for (int idx = tid; idx < 2048; idx += 256) {
    int bb = idx >> 5, q = idx & 31;
    rs4[bb][q] = ((const float4*)rr)[(size_t)(b0 + bb) * 32 + q];
  }
  __syncthreads();

  float acc[16];
#pragma unroll
  for (int m = 0; m < 16; ++m) acc[m] = 0.0f;

  for (int h4 = 0; h4 < 32; ++h4) {
    float w0 = Wout[(size_t)(4 * h4 + 0) * VV + v];
    float w1 = Wout[(size_t)(4 * h4 + 1) * VV + v];
    float w2 = Wout[(size_t)(4 * h4 + 2) * VV + v];
    float w3 = Wout[(size_t)(4 * h4 + 3) * VV + v];
#pragma unroll
    for (int m = 0; m < 16; ++m) {
      float4 rv = rs4[bg * 16 + m][h4];
      float t = rv.x * w0;
      t = fmaf(rv.y, w1, t);
      t = fmaf(rv.z, w2, t);
      t = fmaf(rv.w, w3, t);
      acc[m] += t;
    }
  }
  float bo = bout[v];
#pragma unroll
  for (int m = 0; m < 16; ++m) {
    out[(size_t)(b0 + bg * 16 + m) * VV + v] = acc[m] + bo;
  }
}

// ---------------------------------------------------------------------------
extern "C" void kernel_launch(void* const* d_in, const int* in_sizes, int n_in,
                              void* d_out, int out_size, void* d_ws, size_t ws_size,
                              hipStream_t stream)
{
  const int* seq      = (const int*)d_in[0];
  const float* embed  = (const float*)d_in[1];
  const float* W1     = (const float*)d_in[2];
  const float* b1     = (const float*)d_in[3];
  const float* W2     = (const float*)d_in[4];
  const float* b2     = (const float*)d_in[5];
  const float* gamma  = (const float*)d_in[6];
  const float* beta   = (const float*)d_in[7];
  const float* Wrp    = (const float*)d_in[8];
  const float* brp    = (const float*)d_in[9];
  const float* Wout   = (const float*)d_in[10];
  const float* bout   = (const float*)d_in[11];
  float* out          = (float*)d_out;

  char* ws = (char*)d_ws;
  float* Htab2 = (float*)ws;                         // 32000*136*4 = 17,408,000 B
  float* rr    = (float*)(ws + 17408000);            //    131,072 B

  hipLaunchKernelGGL(build_htab_kernel, dim3(256), dim3(256), 0, stream,
                     embed, W1, b1, W2, b2, gamma, beta, Htab2);
  hipLaunchKernelGGL(scan_kernel, dim3(BB), dim3(256), 0, stream,
                     seq, Htab2, Wrp, brp, rr);
  hipLaunchKernelGGL(out_kernel, dim3(VV / 64, 4), dim3(256), 0, stream,
                     rr, Wout, bout, out);
}

// Round 5
// 1855.091 us; speedup vs baseline: 1.4776x; 1.1275x over previous
//
#include <hip/hip_runtime.h>
#include <hip/hip_bf16.h>

// B=256, L=2048, H=128, V=32000, THR=0.4, LN_EPS=1e-5. All fp32.
// Htab2 row (RS=136 floats, padded for LDS bank-disjointness):
//   [0:64)=h[0..63], [64:68)=pad, [68:132)=h[64..127], [132]=kk, [133]=inv, [134:136) pad.
// Scan: M in VGPRs (pinned kreg), 3-slot LDS k-ring via global_load_lds,
// lgkm-only barriers (no vmcnt drain), explicit vmcnt(1) DMA waits,
// DPP-only reductions, squared-form gate.
// NOTE: skipping xor1 in the e^2 tree means ne2 == ||e||^2 (each distinct row
// counted ONCE). Gate: ne2 > 0.16*kk  <=>  ||e|| > 0.4*||v||.  (Round-4 bug:
// used 0.32 believing ne2 = 2*||e||^2.)

#define BB 256
#define LL 2048
#define HH 128
#define VV 32000
#define RS 136

__device__ __forceinline__ void dma16(const float* g, float* l) {
  __builtin_amdgcn_global_load_lds(
      (const __attribute__((address_space(1))) void*)g,
      (__attribute__((address_space(3))) void*)l,
      16, 0, 0);
}

template <int CTRL>
__device__ __forceinline__ float dppadd(float x) {
  int y = __builtin_amdgcn_update_dpp(0, __float_as_int(x), CTRL, 0xF, 0xF, true);
  return x + __int_as_float(y);
}

__device__ __forceinline__ void barrier_lgkm() {
  asm volatile("s_waitcnt lgkmcnt(0)\n\ts_barrier" ::: "memory");
}
__device__ __forceinline__ void wait_vm1() {
  asm volatile("s_waitcnt vmcnt(1)" ::: "memory");
}
__device__ __forceinline__ void wait_vm0() {
  asm volatile("s_waitcnt vmcnt(0)" ::: "memory");
}

// ---------------------------------------------------------------------------
// Kernel A: Htab2 row = LN(e + relu(e@W1+b1)@W2 + b2) (+ kk, inv), padded layout.
// ---------------------------------------------------------------------------
__global__ __launch_bounds__(256, 1) void build_htab_kernel(
    const float* __restrict__ embed,
    const float* __restrict__ W1,
    const float* __restrict__ b1,
    const float* __restrict__ W2,
    const float* __restrict__ b2,
    const float* __restrict__ gamma,
    const float* __restrict__ beta,
    float* __restrict__ Htab2)
{
  const int tid = threadIdx.x;
  const int j   = tid & 127;
  const int h2  = tid >> 7;

  float w1r[128];
#pragma unroll
  for (int m = 0; m < 128; ++m) w1r[m] = W1[m * 256 + tid];

  const float b1n = b1[tid];
  const float b2j = b2[j];
  const float gj  = gamma[j];
  const float bj  = beta[j];

  __shared__ __align__(16) float4 w2q[64][128];   // 128 KiB
  __shared__ __align__(16) float e_s[128];
  __shared__ __align__(16) float a_s[256];
  __shared__ float p_s[2][128];
  __shared__ float red[8];

  for (int idx = tid; idx < 8192; idx += 256) {
    int n4 = idx >> 7, jj = idx & 127;
    float4 w;
    w.x = W2[(size_t)(4 * n4 + 0) * 128 + jj];
    w.y = W2[(size_t)(4 * n4 + 1) * 128 + jj];
    w.z = W2[(size_t)(4 * n4 + 2) * 128 + jj];
    w.w = W2[(size_t)(4 * n4 + 3) * 128 + jj];
    w2q[n4][jj] = w;
  }
  __syncthreads();

  for (int v = blockIdx.x; v < VV; v += gridDim.x) {
    if (tid < 128) e_s[tid] = embed[(size_t)v * 128 + tid];
    __syncthreads();

    float acc[4] = {b1n, 0.f, 0.f, 0.f};
#pragma unroll
    for (int q = 0; q < 32; ++q) {
      float4 ev = *(const float4*)&e_s[4 * q];
      float t = ev.x * w1r[4 * q + 0];
      t = fmaf(ev.y, w1r[4 * q + 1], t);
      t = fmaf(ev.z, w1r[4 * q + 2], t);
      t = fmaf(ev.w, w1r[4 * q + 3], t);
      acc[q & 3] += t;
    }
    float a = fmaxf((acc[0] + acc[1]) + (acc[2] + acc[3]), 0.0f);
    a_s[tid] = a;
    __syncthreads();

    float p0 = 0.f, p1 = 0.f, p2v = 0.f, p3 = 0.f;
#pragma unroll
    for (int q = 0; q < 32; ++q) {
      int n4 = h2 * 32 + q;
      float4 av = *(const float4*)&a_s[4 * n4];
      float4 wq = w2q[n4][j];
      p0 = fmaf(av.x, wq.x, p0);
      p1 = fmaf(av.y, wq.y, p1);
      p2v = fmaf(av.z, wq.z, p2v);
      p3 = fmaf(av.w, wq.w, p3);
    }
    p_s[h2][j] = (p0 + p1) + (p2v + p3);
    __syncthreads();

    float y = 0.0f;
    if (tid < 128) {
      float ff = p_s[0][tid] + p_s[1][tid] + b2j;
      y = e_s[tid] + ff;
    }
    float s1 = y;
#pragma unroll
    for (int d = 1; d < 64; d <<= 1) s1 += __shfl_xor(s1, d);
    if (tid < 128 && (tid & 63) == 0) red[tid >> 6] = s1;
    __syncthreads();
    float mu = (red[0] + red[1]) * (1.0f / 128.0f);
    float dy = (tid < 128) ? (y - mu) : 0.0f;
    float s2 = dy * dy;
#pragma unroll
    for (int d = 1; d < 64; d <<= 1) s2 += __shfl_xor(s2, d);
    if (tid < 128 && (tid & 63) == 0) red[2 + (tid >> 6)] = s2;
    __syncthreads();
    float hv = 0.0f;
    if (tid < 128) {
      float var = (red[2] + red[3]) * (1.0f / 128.0f);
      hv = dy * (1.0f / sqrtf(var + 1e-5f)) * gj + bj;
      int ofs = tid + ((tid >> 6) << 2);           // padded layout
      Htab2[(size_t)v * RS + ofs] = hv;
    }
    float q2 = hv * hv;
#pragma unroll
    for (int d = 1; d < 64; d <<= 1) q2 += __shfl_xor(q2, d);
    if (tid < 128 && (tid & 63) == 0) red[4 + (tid >> 6)] = q2;
    __syncthreads();
    if (tid == 0) {
      float kk = red[4] + red[5];
      Htab2[(size_t)v * RS + 132] = kk;
      Htab2[(size_t)v * RS + 133] = 1.0f / (kk + 1e-6f);
    }
    __syncthreads();
  }
}

// ---------------------------------------------------------------------------
// Kernel B: per-batch scan. 256 blocks x 256 threads, 1 block/CU.
// ---------------------------------------------------------------------------
__global__ __launch_bounds__(256, 1) void scan_kernel(
    const int* __restrict__ seq,
    const float* __restrict__ Htab2,
    const float* __restrict__ Wrp,
    const float* __restrict__ brp,
    float* __restrict__ rr)
{
  const int b     = blockIdx.x;
  const int tid   = threadIdx.x;
  const int i     = tid >> 1;
  const int half  = tid & 1;
  const int lane  = tid & 63;
  const int wv    = tid >> 6;
  const int iofs  = i + ((i >> 6) << 2);   // padded-row index of h[i]
  const int kbase = half * 68;             // float offset of own column half

  __shared__ int seq_s[LL];
  __shared__ __align__(16) float slots[3][RS];
  __shared__ __align__(16) float red_s[3][4];
  __shared__ __align__(16) float r_s[128];
  __shared__ float p2_s[2][128];

  // prologue DMAs (k0 -> slot0, k1 -> slot1), before seq staging for overlap
  {
    int t0 = seq[(size_t)b * LL + 0];
    int t1 = seq[(size_t)b * LL + 1];
    if (lane < 34) {
      dma16(Htab2 + (size_t)t0 * RS + lane * 4, &slots[0][0]);
      dma16(Htab2 + (size_t)t1 * RS + lane * 4, &slots[1][0]);
    }
  }
  for (int t = tid; t < LL; t += 256) seq_s[t] = seq[(size_t)b * LL + t];
  __syncthreads();   // full drain (incl. prologue DMAs) — once, at start

  float M[64];
#pragma unroll
  for (int m = 0; m < 64; ++m) M[m] = 0.f;

  float4 kreg[16];
  float ki, kk, inv;
  {
    const float4* kp = (const float4*)&slots[0][kbase];
#pragma unroll
    for (int m = 0; m < 16; ++m) kreg[m] = kp[m];
    ki = slots[0][iofs];
    kk = slots[0][132];
    inv = slots[0][133];
#pragma unroll
    for (int m = 0; m < 16; ++m)
      asm volatile("" : "+v"(kreg[m].x), "+v"(kreg[m].y), "+v"(kreg[m].z), "+v"(kreg[m].w));
    asm volatile("" : "+v"(ki), "+v"(kk), "+v"(inv));
  }

  // mode: 1 = issue DMA for k_{t+2}, refill waits vmcnt(1)
  //       2 = no DMA (tail),          refill waits vmcnt(0)
  auto step = [&](int t, int p, int sn, int sd, int mode) {
    if (mode == 1) {                       // DMA k_{t+2} -> slots[sd]
      int tk = seq_s[t + 2];
      if (lane < 34)
        dma16(Htab2 + (size_t)tk * RS + lane * 4, &slots[sd][0]);
    }
    // vp over own 64 columns
    float a0 = 0.f, a1 = 0.f, a2 = 0.f, a3 = 0.f;
#pragma unroll
    for (int m = 0; m < 16; ++m) {
      float4 kv = kreg[m];
      a0 = fmaf(kv.x, M[4 * m + 0], a0);
      a1 = fmaf(kv.y, M[4 * m + 1], a1);
      a2 = fmaf(kv.z, M[4 * m + 2], a2);
      a3 = fmaf(kv.w, M[4 * m + 3], a3);
    }
    float vp = (a0 + a1) + (a2 + a3);
    vp = dppadd<0xB1>(vp);                 // pair halves (xor1)
    float e = fmaf(-vp, inv, ki);
    // ||e||^2: e duplicated per pair -> skip xor1; each distinct row once
    float s = e * e;
    s = dppadd<0x4E>(s);                   // quad_perm [2,3,0,1] : xor2
    s = dppadd<0x141>(s);                  // row_half_mirror     : xor4
    s = dppadd<0x140>(s);                  // row_mirror          : xor8
    s = dppadd<0x142>(s);                  // row_bcast15 accumulate
    s = dppadd<0x143>(s);                  // row_bcast31: lanes 48-63 = wave sum
    if (lane == 63) red_s[p][wv] = s;
    barrier_lgkm();                        // lgkmcnt(0) + s_barrier — NO vmcnt drain

    float4 rv = *(const float4*)red_s[p];
    float ne2 = (rv.x + rv.y) + (rv.z + rv.w);   // = ||e||^2
    float ge = (ne2 > 0.16f * kk) ? e : 0.0f;    // ||e|| > 0.4*||v||
#pragma unroll
    for (int m = 0; m < 16; ++m) {
      float4 kv = kreg[m];
      M[4 * m + 0] = fmaf(ge, kv.x, M[4 * m + 0]);
      M[4 * m + 1] = fmaf(ge, kv.y, M[4 * m + 1]);
      M[4 * m + 2] = fmaf(ge, kv.z, M[4 * m + 2]);
      M[4 * m + 3] = fmaf(ge, kv.w, M[4 * m + 3]);
    }
    // refill kreg <- k_{t+1} from slots[sn]
    if (mode == 1) wait_vm1(); else wait_vm0();
    {
      const float4* kp = (const float4*)&slots[sn][kbase];
#pragma unroll
      for (int m = 0; m < 16; ++m) kreg[m] = kp[m];
      ki = slots[sn][iofs];
      kk = slots[sn][132];
      inv = slots[sn][133];
#pragma unroll
      for (int m = 0; m < 16; ++m)
        asm volatile("" : "+v"(kreg[m].x), "+v"(kreg[m].y), "+v"(kreg[m].z), "+v"(kreg[m].w));
      asm volatile("" : "+v"(ki), "+v"(kk), "+v"(inv));
    }
  };

  // steps 0..2045 (slot t%3 holds k_t; DMA fills (t+2)%3)
  for (int t = 0; t < LL - 2; t += 3) {
    step(t,     0, 1, 2, 1);
    step(t + 1, 1, 2, 0, 1);
    step(t + 2, 2, 0, 1, 1);
  }
  step(LL - 2, 0, 1, 2, 2);   // step 2046: no DMA; refill k_2047 w/ vmcnt(0)

  // r = M_fin @ h(seq[b, L-1])  (kreg = k_2047)
  {
    float a0 = 0.f, a1 = 0.f, a2 = 0.f, a3 = 0.f;
#pragma unroll
    for (int m = 0; m < 16; ++m) {
      float4 kv = kreg[m];
      a0 = fmaf(kv.x, M[4 * m + 0], a0);
      a1 = fmaf(kv.y, M[4 * m + 1], a1);
      a2 = fmaf(kv.z, M[4 * m + 2], a2);
      a3 = fmaf(kv.w, M[4 * m + 3], a3);
    }
    float vp = (a0 + a1) + (a2 + a3);
    vp = dppadd<0xB1>(vp);
    if (half == 0) r_s[i] = vp;
  }
  __syncthreads();

  // rr[b,:] = r @ Wrp + brp
  const int j  = tid & 127;
  const int h2 = tid >> 7;
  float pac[2] = {0.f, 0.f};
#pragma unroll
  for (int m = 0; m < 64; ++m) {
    pac[m & 1] = fmaf(r_s[h2 * 64 + m],
                      Wrp[(size_t)(h2 * 64 + m) * 128 + j], pac[m & 1]);
  }
  p2_s[h2][j] = pac[0] + pac[1];
  __syncthreads();
  if (tid < 128) {
    rr[(size_t)b * 128 + tid] = p2_s[0][tid] + p2_s[1][tid] + brp[tid];
  }
}

// ---------------------------------------------------------------------------
// Kernel C: out[b,v] = rr[b,:] @ Wout[:,v] + bout[v]
// ---------------------------------------------------------------------------
__global__ __launch_bounds__(256, 1) void out_kernel(
    const float* __restrict__ rr,
    const float* __restrict__ Wout,
    const float* __restrict__ bout,
    float* __restrict__ out)
{
  const int tid = threadIdx.x;
  const int v = blockIdx.x * 64 + (tid & 63);
  const int bg = tid >> 6;
  const int b0 = blockIdx.y * 64;

  __shared__ float4 rs4[64][32];
  for (int idx = tid; idx < 2048; idx += 256) {
    int bb = idx >> 5, q = idx & 31;
    rs4[bb][q] = ((const float4*)rr)[(size_t)(b0 + bb) * 32 + q];
  }
  __syncthreads();

  float acc[16];
#pragma unroll
  for (int m = 0; m < 16; ++m) acc[m] = 0.0f;

  for (int h4 = 0; h4 < 32; ++h4) {
    float w0 = Wout[(size_t)(4 * h4 + 0) * VV + v];
    float w1 = Wout[(size_t)(4 * h4 + 1) * VV + v];
    float w2 = Wout[(size_t)(4 * h4 + 2) * VV + v];
    float w3 = Wout[(size_t)(4 * h4 + 3) * VV + v];
#pragma unroll
    for (int m = 0; m < 16; ++m) {
      float4 rv = rs4[bg * 16 + m][h4];
      float t = rv.x * w0;
      t = fmaf(rv.y, w1, t);
      t = fmaf(rv.z, w2, t);
      t = fmaf(rv.w, w3, t);
      acc[m] += t;
    }
  }
  float bo = bout[v];
#pragma unroll
  for (int m = 0; m < 16; ++m) {
    out[(size_t)(b0 + bg * 16 + m) * VV + v] = acc[m] + bo;
  }
}

// ---------------------------------------------------------------------------
extern "C" void kernel_launch(void* const* d_in, const int* in_sizes, int n_in,
                              void* d_out, int out_size, void* d_ws, size_t ws_size,
                              hipStream_t stream)
{
  const int* seq      = (const int*)d_in[0];
  const float* embed  = (const float*)d_in[1];
  const float* W1     = (const float*)d_in[2];
  const float* b1     = (const float*)d_in[3];
  const float* W2     = (const float*)d_in[4];
  const float* b2     = (const float*)d_in[5];
  const float* gamma  = (const float*)d_in[6];
  const float* beta   = (const float*)d_in[7];
  const float* Wrp    = (const float*)d_in[8];
  const float* brp    = (const float*)d_in[9];
  const float* Wout   = (const float*)d_in[10];
  const float* bout   = (const float*)d_in[11];
  float* out          = (float*)d_out;

  char* ws = (char*)d_ws;
  float* Htab2 = (float*)ws;                         // 32000*136*4 = 17,408,000 B
  float* rr    = (float*)(ws + 17408000);            //    131,072 B

  hipLaunchKernelGGL(build_htab_kernel, dim3(256), dim3(256), 0, stream,
                     embed, W1, b1, W2, b2, gamma, beta, Htab2);
  hipLaunchKernelGGL(scan_kernel, dim3(BB), dim3(256), 0, stream,
                     seq, Htab2, Wrp, brp, rr);
  hipLaunchKernelGGL(out_kernel, dim3(VV / 64, 4), dim3(256), 0, stream,
                     rr, Wout, bout, out);
}

// Round 6
// 1467.772 us; speedup vs baseline: 1.8675x; 1.2639x over previous
//
#include <hip/hip_runtime.h>
#include <hip/hip_bf16.h>

// B=256, L=2048, H=128, V=32000, THR=0.4, LN_EPS=1e-5. All fp32.
// Htab2 row (RS=136 floats, padded for LDS bank-disjointness):
//   [0:64)=h[0..63], [64:68)=pad, [68:132)=h[64..127], [132]=kk, [133]=inv.
// Scan: M + double-buffered k fragments in VGPRs, v_pk_fma_f32 packed math,
// 3-slot LDS k-ring via global_load_lds, lgkm-only barriers, vmcnt(1) waits,
// DPP-only reductions, squared-form gate (ne2 = ||e||^2, gate 0.16*kk).

#define BB 256
#define LL 2048
#define HH 128
#define VV 32000
#define RS 136

typedef float f32x2 __attribute__((ext_vector_type(2)));

__device__ __forceinline__ void dma16(const float* g, float* l) {
  __builtin_amdgcn_global_load_lds(
      (const __attribute__((address_space(1))) void*)g,
      (__attribute__((address_space(3))) void*)l,
      16, 0, 0);
}

template <int CTRL>
__device__ __forceinline__ float dppadd(float x) {
  int y = __builtin_amdgcn_update_dpp(0, __float_as_int(x), CTRL, 0xF, 0xF, true);
  return x + __int_as_float(y);
}

// d = a*b + d  (packed 2x fp32)
__device__ __forceinline__ void pkfma(f32x2& d, f32x2 a, f32x2 b) {
  asm("v_pk_fma_f32 %0, %1, %2, %0" : "+v"(d) : "v"(a), "v"(b));
}

__device__ __forceinline__ void barrier_lgkm() {
  asm volatile("s_waitcnt lgkmcnt(0)\n\ts_barrier" ::: "memory");
}
__device__ __forceinline__ void wait_vm1() {
  asm volatile("s_waitcnt vmcnt(1)" ::: "memory");
}
__device__ __forceinline__ void wait_vm0() {
  asm volatile("s_waitcnt vmcnt(0)" ::: "memory");
}

// ---------------------------------------------------------------------------
// Kernel A: Htab2 row = LN(e + relu(e@W1+b1)@W2 + b2) (+ kk, inv), padded.
// DPP reduction trees; fused mean/meansq (var = E[y^2] - mu^2).
// ---------------------------------------------------------------------------
__global__ __launch_bounds__(256, 1) void build_htab_kernel(
    const float* __restrict__ embed,
    const float* __restrict__ W1,
    const float* __restrict__ b1,
    const float* __restrict__ W2,
    const float* __restrict__ b2,
    const float* __restrict__ gamma,
    const float* __restrict__ beta,
    float* __restrict__ Htab2)
{
  const int tid = threadIdx.x;
  const int j   = tid & 127;
  const int h2  = tid >> 7;

  float w1r[128];
#pragma unroll
  for (int m = 0; m < 128; ++m) w1r[m] = W1[m * 256 + tid];

  const float b1n = b1[tid];
  const float b2j = b2[j];
  const float gj  = gamma[j];
  const float bj  = beta[j];

  __shared__ __align__(16) float4 w2q[64][128];   // 128 KiB
  __shared__ __align__(16) float e_s[128];
  __shared__ __align__(16) float a_s[256];
  __shared__ float p_s[2][128];
  __shared__ float red[8];

  for (int idx = tid; idx < 8192; idx += 256) {
    int n4 = idx >> 7, jj = idx & 127;
    float4 w;
    w.x = W2[(size_t)(4 * n4 + 0) * 128 + jj];
    w.y = W2[(size_t)(4 * n4 + 1) * 128 + jj];
    w.z = W2[(size_t)(4 * n4 + 2) * 128 + jj];
    w.w = W2[(size_t)(4 * n4 + 3) * 128 + jj];
    w2q[n4][jj] = w;
  }
  __syncthreads();

  for (int v = blockIdx.x; v < VV; v += gridDim.x) {
    if (tid < 128) e_s[tid] = embed[(size_t)v * 128 + tid];
    __syncthreads();

    float acc[4] = {b1n, 0.f, 0.f, 0.f};
#pragma unroll
    for (int q = 0; q < 32; ++q) {
      float4 ev = *(const float4*)&e_s[4 * q];
      float t = ev.x * w1r[4 * q + 0];
      t = fmaf(ev.y, w1r[4 * q + 1], t);
      t = fmaf(ev.z, w1r[4 * q + 2], t);
      t = fmaf(ev.w, w1r[4 * q + 3], t);
      acc[q & 3] += t;
    }
    float a = fmaxf((acc[0] + acc[1]) + (acc[2] + acc[3]), 0.0f);
    a_s[tid] = a;
    __syncthreads();

    float p0 = 0.f, p1 = 0.f, p2v = 0.f, p3 = 0.f;
#pragma unroll
    for (int q = 0; q < 32; ++q) {
      int n4 = h2 * 32 + q;
      float4 av = *(const float4*)&a_s[4 * n4];
      float4 wq = w2q[n4][j];
      p0 = fmaf(av.x, wq.x, p0);
      p1 = fmaf(av.y, wq.y, p1);
      p2v = fmaf(av.z, wq.z, p2v);
      p3 = fmaf(av.w, wq.w, p3);
    }
    p_s[h2][j] = (p0 + p1) + (p2v + p3);
    __syncthreads();

    float y = 0.0f;
    if (tid < 128) {
      float ff = p_s[0][tid] + p_s[1][tid] + b2j;
      y = e_s[tid] + ff;
    }
    // fused sum(y), sum(y^2): two interleaved DPP trees
    float s1 = y, s2 = y * y;
    s1 = dppadd<0xB1>(s1);  s2 = dppadd<0xB1>(s2);
    s1 = dppadd<0x4E>(s1);  s2 = dppadd<0x4E>(s2);
    s1 = dppadd<0x141>(s1); s2 = dppadd<0x141>(s2);
    s1 = dppadd<0x140>(s1); s2 = dppadd<0x140>(s2);
    s1 = dppadd<0x142>(s1); s2 = dppadd<0x142>(s2);
    s1 = dppadd<0x143>(s1); s2 = dppadd<0x143>(s2);
    if (tid < 128 && (tid & 63) == 63) {
      red[tid >> 6] = s1;
      red[2 + (tid >> 6)] = s2;
    }
    __syncthreads();
    float mu = (red[0] + red[1]) * (1.0f / 128.0f);
    float ms = (red[2] + red[3]) * (1.0f / 128.0f);
    float var = ms - mu * mu;
    float hv = 0.0f;
    if (tid < 128) {
      float dy = y - mu;
      hv = dy * (1.0f / sqrtf(var + 1e-5f)) * gj + bj;
      int ofs = tid + ((tid >> 6) << 2);           // padded layout
      Htab2[(size_t)v * RS + ofs] = hv;
    }
    float q2 = hv * hv;
    q2 = dppadd<0xB1>(q2);
    q2 = dppadd<0x4E>(q2);
    q2 = dppadd<0x141>(q2);
    q2 = dppadd<0x140>(q2);
    q2 = dppadd<0x142>(q2);
    q2 = dppadd<0x143>(q2);
    if (tid < 128 && (tid & 63) == 63) red[4 + (tid >> 6)] = q2;
    __syncthreads();
    if (tid == 0) {
      float kk = red[4] + red[5];
      Htab2[(size_t)v * RS + 132] = kk;
      Htab2[(size_t)v * RS + 133] = 1.0f / (kk + 1e-6f);
    }
    __syncthreads();
  }
}

// ---------------------------------------------------------------------------
// Kernel B: per-batch scan. 256 blocks x 256 threads, 1 block/CU.
// Thread (i=tid>>1, half=tid&1) owns M[i][64*half..+63] as 32 f32x2.
// ---------------------------------------------------------------------------
__global__ __launch_bounds__(256, 1) void scan_kernel(
    const int* __restrict__ seq,
    const float* __restrict__ Htab2,
    const float* __restrict__ Wrp,
    const float* __restrict__ brp,
    float* __restrict__ rr)
{
  const int b     = blockIdx.x;
  const int tid   = threadIdx.x;
  const int i     = tid >> 1;
  const int half  = tid & 1;
  const int lane  = tid & 63;
  const int wv    = tid >> 6;
  const int iofs  = i + ((i >> 6) << 2);   // padded-row index of h[i]
  const int kbase = half * 68;             // float offset of own column half

  __shared__ int seq_s[LL];
  __shared__ __align__(16) float slots[3][RS];
  __shared__ __align__(16) float red_s[3][4];
  __shared__ __align__(16) float r_s[128];
  __shared__ float p2_s[2][128];

  // prologue DMAs (k0 -> slot0, k1 -> slot1)
  {
    int t0 = seq[(size_t)b * LL + 0];
    int t1 = seq[(size_t)b * LL + 1];
    if (lane < 34) {
      dma16(Htab2 + (size_t)t0 * RS + lane * 4, &slots[0][0]);
      dma16(Htab2 + (size_t)t1 * RS + lane * 4, &slots[1][0]);
    }
  }
  for (int t = tid; t < LL; t += 256) seq_s[t] = seq[(size_t)b * LL + t];
  __syncthreads();   // full drain (incl. prologue DMAs) — once, at start

  f32x2 M2[32];
#pragma unroll
  for (int m = 0; m < 32; ++m) M2[m] = f32x2{0.f, 0.f};

  f32x2 kA[32], kB[32];
  float kiA, kkA, invA, kiB, kkB, invB;
  {
    const float4* kp = (const float4*)&slots[0][kbase];
#pragma unroll
    for (int m = 0; m < 16; ++m) {
      float4 tq = kp[m];
      kA[2 * m]     = f32x2{tq.x, tq.y};
      kA[2 * m + 1] = f32x2{tq.z, tq.w};
    }
    kiA = slots[0][iofs];
    float2 kv = *(const float2*)&slots[0][132];
    kkA = kv.x; invA = kv.y;
#pragma unroll
    for (int m = 0; m < 32; ++m) asm volatile("" : "+v"(kA[m]));
    asm volatile("" : "+v"(kiA), "+v"(kkA), "+v"(invA));
  }

  // mode 1: issue DMA k_{t+2}, refill waits vmcnt(1); mode 2: tail, vmcnt(0).
  auto step = [&](f32x2 (&kc)[32], float ki_c, float kk_c, float inv_c,
                  f32x2 (&kn)[32], float& ki_n, float& kk_n, float& inv_n,
                  int t, int p, int sn, int sd, int mode) {
    if (mode == 1) {
      int tk = seq_s[t + 2];
      if (lane < 34)
        dma16(Htab2 + (size_t)tk * RS + lane * 4, &slots[sd][0]);
    }
    // vp over own 64 columns (packed)
    f32x2 a0{0.f,0.f}, a1{0.f,0.f}, a2{0.f,0.f}, a3{0.f,0.f};
#pragma unroll
    for (int m = 0; m < 8; ++m) {
      pkfma(a0, kc[4 * m + 0], M2[4 * m + 0]);
      pkfma(a1, kc[4 * m + 1], M2[4 * m + 1]);
      pkfma(a2, kc[4 * m + 2], M2[4 * m + 2]);
      pkfma(a3, kc[4 * m + 3], M2[4 * m + 3]);
    }
    float vp = ((a0.x + a0.y) + (a1.x + a1.y)) + ((a2.x + a2.y) + (a3.x + a3.y));
    vp = dppadd<0xB1>(vp);                 // pair halves (xor1)
    float e = fmaf(-vp, inv_c, ki_c);
    // ||e||^2 (each distinct row once; ne2 == ||e||^2)
    float s = e * e;
    s = dppadd<0x4E>(s);
    s = dppadd<0x141>(s);
    s = dppadd<0x140>(s);
    s = dppadd<0x142>(s);
    s = dppadd<0x143>(s);
    if (lane == 63) red_s[p][wv] = s;
    barrier_lgkm();                        // lgkmcnt(0)+s_barrier, NO vmcnt drain

    float4 rv = *(const float4*)red_s[p];  // issue early: latency overlaps refill
    if (mode == 1) wait_vm1(); else wait_vm0();
    {                                      // refill k_{t+1} -> kn (consumed next step)
      const float4* kp = (const float4*)&slots[sn][kbase];
#pragma unroll
      for (int m = 0; m < 16; ++m) {
        float4 tq = kp[m];
        kn[2 * m]     = f32x2{tq.x, tq.y};
        kn[2 * m + 1] = f32x2{tq.z, tq.w};
      }
      ki_n = slots[sn][iofs];
      float2 kv = *(const float2*)&slots[sn][132];
      kk_n = kv.x; inv_n = kv.y;
    }
    float ne2 = (rv.x + rv.y) + (rv.z + rv.w);
    float ge = (ne2 > 0.16f * kk_c) ? e : 0.0f;   // ||e|| > 0.4*||v||
    f32x2 ev{ge, ge};
#pragma unroll
    for (int m = 0; m < 32; ++m) pkfma(M2[m], ev, kc[m]);
    // pin kn AFTER the update so its loads hide under red-read + update
#pragma unroll
    for (int m = 0; m < 32; ++m) asm volatile("" : "+v"(kn[m]));
    asm volatile("" : "+v"(ki_n), "+v"(kk_n), "+v"(inv_n));
  };

  // steps 0..2045 (2046 = 6*341). Slot t%3 holds k_t; DMA fills (t+2)%3.
  for (int t = 0; t < LL - 2; t += 6) {
    step(kA, kiA, kkA, invA, kB, kiB, kkB, invB, t + 0, 0, 1, 2, 1);
    step(kB, kiB, kkB, invB, kA, kiA, kkA, invA, t + 1, 1, 2, 0, 1);
    step(kA, kiA, kkA, invA, kB, kiB, kkB, invB, t + 2, 2, 0, 1, 1);
    step(kB, kiB, kkB, invB, kA, kiA, kkA, invA, t + 3, 0, 1, 2, 1);
    step(kA, kiA, kkA, invA, kB, kiB, kkB, invB, t + 4, 1, 2, 0, 1);
    step(kB, kiB, kkB, invB, kA, kiA, kkA, invA, t + 5, 2, 0, 1, 1);
  }
  // step 2046: kA = k_2046; refill kB = k_2047 with vmcnt(0)
  step(kA, kiA, kkA, invA, kB, kiB, kkB, invB, LL - 2, 0, 1, 2, 2);

  // r = M_fin @ h(seq[b, L-1])  (kB = k_2047)
  {
    f32x2 a0{0.f,0.f}, a1{0.f,0.f}, a2{0.f,0.f}, a3{0.f,0.f};
#pragma unroll
    for (int m = 0; m < 8; ++m) {
      pkfma(a0, kB[4 * m + 0], M2[4 * m + 0]);
      pkfma(a1, kB[4 * m + 1], M2[4 * m + 1]);
      pkfma(a2, kB[4 * m + 2], M2[4 * m + 2]);
      pkfma(a3, kB[4 * m + 3], M2[4 * m + 3]);
    }
    float vp = ((a0.x + a0.y) + (a1.x + a1.y)) + ((a2.x + a2.y) + (a3.x + a3.y));
    vp = dppadd<0xB1>(vp);
    if (half == 0) r_s[i] = vp;
  }
  __syncthreads();

  // rr[b,:] = r @ Wrp + brp
  const int j  = tid & 127;
  const int h2 = tid >> 7;
  float pac[2] = {0.f, 0.f};
#pragma unroll
  for (int m = 0; m < 64; ++m) {
    pac[m & 1] = fmaf(r_s[h2 * 64 + m],
                      Wrp[(size_t)(h2 * 64 + m) * 128 + j], pac[m & 1]);
  }
  p2_s[h2][j] = pac[0] + pac[1];
  __syncthreads();
  if (tid < 128) {
    rr[(size_t)b * 128 + tid] = p2_s[0][tid] + p2_s[1][tid] + brp[tid];
  }
}

// ---------------------------------------------------------------------------
// Kernel C: out[b,v] = rr[b,:] @ Wout[:,v] + bout[v]
// ---------------------------------------------------------------------------
__global__ __launch_bounds__(256, 1) void out_kernel(
    const float* __restrict__ rr,
    const float* __restrict__ Wout,
    const float* __restrict__ bout,
    float* __restrict__ out)
{
  const int tid = threadIdx.x;
  const int v = blockIdx.x * 64 + (tid & 63);
  const int bg = tid >> 6;
  const int b0 = blockIdx.y * 64;

  __shared__ float4 rs4[64][32];
  for (int idx = tid; idx < 2048; idx += 256) {
    int bb = idx >> 5, q = idx & 31;
    rs4[bb][q] = ((const float4*)rr)[(size_t)(b0 + bb) * 32 + q];
  }
  __syncthreads();

  float acc[16];
#pragma unroll
  for (int m = 0; m < 16; ++m) acc[m] = 0.0f;

  for (int h4 = 0; h4 < 32; ++h4) {
    float w0 = Wout[(size_t)(4 * h4 + 0) * VV + v];
    float w1 = Wout[(size_t)(4 * h4 + 1) * VV + v];
    float w2 = Wout[(size_t)(4 * h4 + 2) * VV + v];
    float w3 = Wout[(size_t)(4 * h4 + 3) * VV + v];
#pragma unroll
    for (int m = 0; m < 16; ++m) {
      float4 rv = rs4[bg * 16 + m][h4];
      float t = rv.x * w0;
      t = fmaf(rv.y, w1, t);
      t = fmaf(rv.z, w2, t);
      t = fmaf(rv.w, w3, t);
      acc[m] += t;
    }
  }
  float bo = bout[v];
#pragma unroll
  for (int m = 0; m < 16; ++m) {
    out[(size_t)(b0 + bg * 16 + m) * VV + v] = acc[m] + bo;
  }
}

// ---------------------------------------------------------------------------
extern "C" void kernel_launch(void* const* d_in, const int* in_sizes, int n_in,
                              void* d_out, int out_size, void* d_ws, size_t ws_size,
                              hipStream_t stream)
{
  const int* seq      = (const int*)d_in[0];
  const float* embed  = (const float*)d_in[1];
  const float* W1     = (const float*)d_in[2];
  const float* b1     = (const float*)d_in[3];
  const float* W2     = (const float*)d_in[4];
  const float* b2     = (const float*)d_in[5];
  const float* gamma  = (const float*)d_in[6];
  const float* beta   = (const float*)d_in[7];
  const float* Wrp    = (const float*)d_in[8];
  const float* brp    = (const float*)d_in[9];
  const float* Wout   = (const float*)d_in[10];
  const float* bout   = (const float*)d_in[11];
  float* out          = (float*)d_out;

  char* ws = (char*)d_ws;
  float* Htab2 = (float*)ws;                         // 32000*136*4 = 17,408,000 B
  float* rr    = (float*)(ws + 17408000);            //    131,072 B

  hipLaunchKernelGGL(build_htab_kernel, dim3(256), dim3(256), 0, stream,
                     embed, W1, b1, W2, b2, gamma, beta, Htab2);
  hipLaunchKernelGGL(scan_kernel, dim3(BB), dim3(256), 0, stream,
                     seq, Htab2, Wrp, brp, rr);
  hipLaunchKernelGGL(out_kernel, dim3(VV / 64, 4), dim3(256), 0, stream,
                     rr, Wout, bout, out);
}